// Round 9
// baseline (1098.745 us; speedup 1.0000x reference)
//
#include <hip/hip_runtime.h>

typedef unsigned int   u32;
typedef unsigned short u16;
typedef __attribute__((ext_vector_type(8))) short bf16x8;
typedef __attribute__((ext_vector_type(4))) float f32x4;

__device__ __forceinline__ u16 f2b(float f) {
    u32 u = __float_as_uint(f);
    u += 0x7FFFu + ((u >> 16) & 1u);   // round-to-nearest-even
    return (u16)(u >> 16);
}
__device__ __forceinline__ float b2f_lo(u32 v) { return __uint_as_float(v << 16); }
__device__ __forceinline__ float b2f_hi(u32 v) { return __uint_as_float(v & 0xFFFF0000u); }
__device__ __forceinline__ u32 pack2(float a, float b) {
    return (u32)f2b(a) | ((u32)f2b(b) << 16);
}

#define BSHIFT 7                      // 128 nodes per bucket
#define BNODES 128
#define BIN_CHUNK 2048                // edges per k_bin block
#define T1STRIDE 68                   // layer-1 LDS tile row stride (16B-aligned rows)
#define T2STRIDE 36                   // layer-2 LDS tile row stride

// ---------------- init: zero bucket counters + pack W1 MFMA B-fragments ----------------

__global__ void k_init(const float* __restrict__ W1, bf16x8* __restrict__ Wpack,
                       int* __restrict__ bcnt, int NB) {
    int tid = threadIdx.x;
    for (int i = tid; i < NB; i += 256) bcnt[i] = 0;
    if (tid < 64) {
        int lane = tid;
#pragma unroll
        for (int ct = 0; ct < 4; ct++) {
#pragma unroll
            for (int ks = 0; ks < 4; ks++) {
                bf16x8 h;
#pragma unroll
                for (int j = 0; j < 8; j++) {
                    int k = ks * 32 + ((lane >> 4) << 3) + j;
                    int col = ct * 16 + (lane & 15);
                    h[j] = (short)f2b(W1[k * 64 + col]);
                }
                Wpack[(ct * 4 + ks) * 64 + lane] = h;
            }
        }
    }
}

// ---------------- bucketed edge binning (padded regions, no global scan) ----------------
// key = (dstLocal<<24) | src, written bucket-ordered in contiguous runs.

__global__ __launch_bounds__(256) void k_bin(const int* __restrict__ src,
                                             const int* __restrict__ dst,
                                             int* __restrict__ bcnt,
                                             u32* __restrict__ binned,
                                             int E, int NB, int CAP) {
    __shared__ int lh[1024], ls[1024], gb[1024], sh[256];
    __shared__ u32 stage[BIN_CHUNK];
    __shared__ u16 sbuck[BIN_CHUNK];
    int tid = threadIdx.x;
    int base = blockIdx.x * BIN_CHUNK;
    int cnt = E - base;
    if (cnt > BIN_CHUNK) cnt = BIN_CHUNK;

    for (int i = tid; i < 1024; i += 256) lh[i] = 0;
    __syncthreads();

    const int T = BIN_CHUNK / 256;
    int bk[T], r[T];
    u32 key[T];
#pragma unroll
    for (int t = 0; t < T; t++) {
        int i = base + t * 256 + tid;
        bk[t] = -1;
        if (i < E) {
            int dv = dst[i];
            bk[t] = dv >> BSHIFT;
            key[t] = ((u32)(dv & (BNODES - 1)) << 24) | (u32)src[i];
            r[t] = atomicAdd(&lh[bk[t]], 1);
        }
    }
    __syncthreads();
    {   // exclusive scan of lh[1024] with 256 threads (4 per thread)
        int a0 = lh[4 * tid], a1 = lh[4 * tid + 1], a2 = lh[4 * tid + 2], a3 = lh[4 * tid + 3];
        int s01 = a0 + a1;
        int s = s01 + a2 + a3;
        sh[tid] = s;
        __syncthreads();
        for (int dd = 1; dd < 256; dd <<= 1) {
            int x = tid >= dd ? sh[tid - dd] : 0;
            __syncthreads();
            sh[tid] += x;
            __syncthreads();
        }
        int excl = sh[tid] - s;
        ls[4 * tid] = excl;
        ls[4 * tid + 1] = excl + a0;
        ls[4 * tid + 2] = excl + s01;
        ls[4 * tid + 3] = excl + s01 + a2;
    }
    for (int b = tid; b < NB; b += 256) {
        int c = lh[b];
        gb[b] = c ? atomicAdd(&bcnt[b], c) : 0;
    }
    __syncthreads();
#pragma unroll
    for (int t = 0; t < T; t++) {
        if (bk[t] >= 0) {
            int slot = ls[bk[t]] + r[t];
            stage[slot] = key[t];
            sbuck[slot] = (u16)bk[t];
        }
    }
    __syncthreads();
    for (int j = tid; j < cnt; j += 256) {
        u32 e = stage[j];
        int b = sbuck[j];
        int p = gb[b] + (j - ls[b]);
        if (p < CAP) binned[(size_t)b * CAP + p] = e;
    }
}

// ---------------- fused dinv + gemm1 ----------------
// one block per bucket. Phase 1: per-node degree histogram -> dinv (no scan, no scatter).
// Phase 2: MFMA transform h1b = bf16((x @ W1) * dinv) for this bucket's 128 rows.

__global__ __launch_bounds__(256) void k_dinv_gemm1(const u32* __restrict__ binned,
                                                    const int* __restrict__ bcnt,
                                                    const bf16x8* __restrict__ Wpack,
                                                    const float* __restrict__ x,
                                                    float* __restrict__ dinv,
                                                    u16* __restrict__ h1b,
                                                    int n, int CAP) {
    __shared__ int lcnt[BNODES];
    __shared__ float dinv_sh[BNODES];
    int tid = threadIdx.x;
    int b = blockIdx.x;
    size_t base = (size_t)b * CAP;
    int nodeBase = b << BSHIFT;
    int ecnt = bcnt[b];
    if (ecnt > CAP) ecnt = CAP;
    if (tid < BNODES) lcnt[tid] = 0;
    __syncthreads();
    for (int j = tid; j < ecnt; j += 256)
        atomicAdd(&lcnt[binned[base + j] >> 24], 1);
    __syncthreads();
    if (tid < BNODES) {
        float dv = rsqrtf((float)(lcnt[tid] + 1));
        dinv_sh[tid] = dv;
        int node = nodeBase + tid;
        if (node < n) dinv[node] = dv;
    }
    __syncthreads();

    // phase 2: gemm1 (2 row-tiles of 16 per wave)
    int wv = tid >> 6, lane = tid & 63;
    bf16x8 bfr[16];
#pragma unroll
    for (int f = 0; f < 16; f++) bfr[f] = Wpack[f * 64 + lane];

    for (int t = wv; t < 8; t += 4) {
        int rowBase = nodeBase + t * 16;
        if (rowBase >= n) break;
        f32x4 acc[4];
#pragma unroll
        for (int ct = 0; ct < 4; ct++) acc[ct] = (f32x4){0.f, 0.f, 0.f, 0.f};

        int r0 = rowBase + (lane & 15);
        if (r0 >= n) r0 = n - 1;           // clamp: D row i only uses A row i
        const float* xr = x + (size_t)r0 * 128 + ((lane >> 4) << 3);
#pragma unroll
        for (int ks = 0; ks < 4; ks++) {
            float4 p0 = *(const float4*)(xr + ks * 32);
            float4 p1 = *(const float4*)(xr + ks * 32 + 4);
            bf16x8 a;
            a[0] = (short)f2b(p0.x); a[1] = (short)f2b(p0.y);
            a[2] = (short)f2b(p0.z); a[3] = (short)f2b(p0.w);
            a[4] = (short)f2b(p1.x); a[5] = (short)f2b(p1.y);
            a[6] = (short)f2b(p1.z); a[7] = (short)f2b(p1.w);
#pragma unroll
            for (int ct = 0; ct < 4; ct++)
                acc[ct] = __builtin_amdgcn_mfma_f32_16x16x32_bf16(a, bfr[ct * 4 + ks], acc[ct], 0, 0, 0);
        }
        // C/D layout: col = lane&15, row = (lane>>4)*4 + r  [m89-verified]
        int lrb = t * 16 + ((lane >> 4) << 2);
#pragma unroll
        for (int r = 0; r < 4; r++) {
            int lrow = lrb + r;
            int row = nodeBase + lrow;
            float dv = dinv_sh[lrow];
#pragma unroll
            for (int ct = 0; ct < 4; ct++) {
                float o = acc[ct][r] * dv;
                float onb = __shfl_xor(o, 1);   // neighbor col
                if (!(lane & 1) && row < n) {
                    *(u32*)&h1b[(size_t)row * 64 + ct * 16 + (lane & 15)] = pack2(o, onb);
                }
            }
        }
    }
}

// ---------------- bucket-LDS agg1 + relu + gemm2 ----------------
// one block per bucket: gather h1p rows for the bucket's edges, ds_add_f32 into
// an LDS fp32 tile; then self-loop + dinv + b1 + relu in place; then gemm2 -> h2b.

__global__ __launch_bounds__(256) void k_agg1gemm2_b(const u16* __restrict__ h1b,
                                                     const u32* __restrict__ binned,
                                                     const int* __restrict__ bcnt,
                                                     const float* __restrict__ dinv,
                                                     const float* __restrict__ b1,
                                                     const float* __restrict__ W2,
                                                     u16* __restrict__ h2b, int n) {
    __shared__ float tile[BNODES * T1STRIDE];
    int tid = threadIdx.x;
    int b = blockIdx.x;
    int nodeBase = b << BSHIFT;
    size_t base = (size_t)b * (size_t)0 + (size_t)b;  // placeholder (overwritten below)
    base = (size_t)b;                                  // silence unused warn path
    // (actual base computed with CAP below)
    extern __shared__ char _dummy[];                   // no dynamic LDS used
    (void)_dummy;

    // zero tile
    for (int i = tid; i < BNODES * T1STRIDE; i += 256) tile[i] = 0.f;

    int hw = tid >> 5;            // 0..7 half-waves
    int c2 = tid & 31;            // channel pair 2c2, 2c2+1
    // gemm2 roles (per 64-lane wave)
    int lane = tid & 63, wv = tid >> 6;
    int half = lane >> 5, c2o = lane & 31;
    float w2r[32];
#pragma unroll
    for (int kk = 0; kk < 32; kk++) w2r[kk] = W2[(half * 32 + kk) * 32 + c2o];
    float b1a = b1[2 * c2], b1b = b1[2 * c2 + 1];
    __syncthreads();

    int CAP = (int)0;  // passed via bcnt? no — recompute: see launch (CAP encoded below)
    // NOTE: CAP passed through gridDim trick is fragile; instead it's a kernel arg in
    // the real signature. (see below)
    (void)CAP;
    // --- this body continues in k_agg1gemm2_b_impl pattern; kept inline via macro-free code ---
    // (structured below with CAP as argument)
    // unreachable placeholder
    (void)base; (void)hw; (void)c2; (void)wv; (void)w2r; (void)b1a; (void)b1b;
    (void)nodeBase; (void)n; (void)h1b; (void)binned; (void)bcnt; (void)dinv; (void)h2b;
}

// real implementation with CAP argument
__global__ __launch_bounds__(256) void k_agg1gemm2_c(const u16* __restrict__ h1b,
                                                     const u32* __restrict__ binned,
                                                     const int* __restrict__ bcnt,
                                                     const float* __restrict__ dinv,
                                                     const float* __restrict__ b1,
                                                     const float* __restrict__ W2,
                                                     u16* __restrict__ h2b,
                                                     int n, int CAP) {
    __shared__ float tile[BNODES * T1STRIDE];
    int tid = threadIdx.x;
    int b = blockIdx.x;
    size_t base = (size_t)b * CAP;
    int nodeBase = b << BSHIFT;
    int ecnt = bcnt[b];
    if (ecnt > CAP) ecnt = CAP;

    for (int i = tid; i < BNODES * T1STRIDE; i += 256) tile[i] = 0.f;

    int hw = tid >> 5;            // half-wave id 0..7
    int c2 = tid & 31;
    int lane = tid & 63, wv = tid >> 6;
    int half = lane >> 5, c2o = lane & 31;
    float w2r[32];
#pragma unroll
    for (int kk = 0; kk < 32; kk++) w2r[kk] = W2[(half * 32 + kk) * 32 + c2o];
    float b1a = b1[2 * c2], b1b = b1[2 * c2 + 1];
    __syncthreads();

    // phase B: edge gather + LDS fp32 accumulate (half-wave per edge, 4 in flight)
    const u32* keys = binned + base;
    int j = hw;
    for (; j + 24 < ecnt; j += 32) {
        u32 k0 = keys[j], k1 = keys[j + 8], k2 = keys[j + 16], k3 = keys[j + 24];
        u32 v0 = *(const u32*)&h1b[(size_t)(k0 & 0xFFFFFFu) * 64 + 2 * c2];
        u32 v1 = *(const u32*)&h1b[(size_t)(k1 & 0xFFFFFFu) * 64 + 2 * c2];
        u32 v2 = *(const u32*)&h1b[(size_t)(k2 & 0xFFFFFFu) * 64 + 2 * c2];
        u32 v3 = *(const u32*)&h1b[(size_t)(k3 & 0xFFFFFFu) * 64 + 2 * c2];
        float* t0 = &tile[(k0 >> 24) * T1STRIDE + 2 * c2];
        float* t1 = &tile[(k1 >> 24) * T1STRIDE + 2 * c2];
        float* t2 = &tile[(k2 >> 24) * T1STRIDE + 2 * c2];
        float* t3 = &tile[(k3 >> 24) * T1STRIDE + 2 * c2];
        atomicAdd(t0, b2f_lo(v0)); atomicAdd(t0 + 1, b2f_hi(v0));
        atomicAdd(t1, b2f_lo(v1)); atomicAdd(t1 + 1, b2f_hi(v1));
        atomicAdd(t2, b2f_lo(v2)); atomicAdd(t2 + 1, b2f_hi(v2));
        atomicAdd(t3, b2f_lo(v3)); atomicAdd(t3 + 1, b2f_hi(v3));
    }
    for (; j < ecnt; j += 8) {
        u32 k0 = keys[j];
        u32 v0 = *(const u32*)&h1b[(size_t)(k0 & 0xFFFFFFu) * 64 + 2 * c2];
        float* t0 = &tile[(k0 >> 24) * T1STRIDE + 2 * c2];
        atomicAdd(t0, b2f_lo(v0)); atomicAdd(t0 + 1, b2f_hi(v0));
    }
    __syncthreads();

    // phase B2: self-loop + dinv scale + bias + relu, in place (half-wave per node)
    for (int node = hw; node < BNODES; node += 8) {
        int gnode = nodeBase + node;
        if (gnode >= n) break;
        u32 hv = *(const u32*)&h1b[(size_t)gnode * 64 + 2 * c2];
        float dv = dinv[gnode];
        float t0 = tile[node * T1STRIDE + 2 * c2]     + b2f_lo(hv);
        float t1 = tile[node * T1STRIDE + 2 * c2 + 1] + b2f_hi(hv);
        t0 = t0 * dv + b1a;
        t1 = t1 * dv + b1b;
        tile[node * T1STRIDE + 2 * c2]     = t0 > 0.f ? t0 : 0.f;
        tile[node * T1STRIDE + 2 * c2 + 1] = t1 > 0.f ? t1 : 0.f;
    }
    __syncthreads();

    // phase C: gemm2 (wave per node, 32 nodes per wave)
    for (int node = wv * 32; node < wv * 32 + 32; node++) {
        int gnode = nodeBase + node;
        if (gnode >= n) break;
        float acc = 0.f;
#pragma unroll
        for (int kk = 0; kk < 32; kk += 4) {
            float4 av = *(const float4*)&tile[node * T1STRIDE + half * 32 + kk];
            acc += av.x * w2r[kk] + av.y * w2r[kk + 1] + av.z * w2r[kk + 2] + av.w * w2r[kk + 3];
        }
        acc += __shfl_xor(acc, 32);
        if (half == 0) {
            float dv = dinv[gnode];
            h2b[(size_t)gnode * 32 + c2o] = f2b(acc * dv);
        }
    }
}

// ---------------- bucket-LDS agg2 -> out ----------------

__global__ __launch_bounds__(256) void k_agg2_b(const u16* __restrict__ h2b,
                                                const u32* __restrict__ binned,
                                                const int* __restrict__ bcnt,
                                                const float* __restrict__ dinv,
                                                const float* __restrict__ b2,
                                                float* __restrict__ out,
                                                int n, int CAP) {
    __shared__ float tile[BNODES * T2STRIDE];
    int tid = threadIdx.x;
    int b = blockIdx.x;
    size_t base = (size_t)b * CAP;
    int nodeBase = b << BSHIFT;
    int ecnt = bcnt[b];
    if (ecnt > CAP) ecnt = CAP;

    for (int i = tid; i < BNODES * T2STRIDE; i += 256) tile[i] = 0.f;
    __syncthreads();

    int qw = tid >> 4;            // quarter-wave id 0..15
    int c2 = tid & 15;            // channel pair
    const u32* keys = binned + base;
    int j = qw;
    for (; j + 48 < ecnt; j += 64) {
        u32 k0 = keys[j], k1 = keys[j + 16], k2 = keys[j + 32], k3 = keys[j + 48];
        u32 v0 = *(const u32*)&h2b[(size_t)(k0 & 0xFFFFFFu) * 32 + 2 * c2];
        u32 v1 = *(const u32*)&h2b[(size_t)(k1 & 0xFFFFFFu) * 32 + 2 * c2];
        u32 v2 = *(const u32*)&h2b[(size_t)(k2 & 0xFFFFFFu) * 32 + 2 * c2];
        u32 v3 = *(const u32*)&h2b[(size_t)(k3 & 0xFFFFFFu) * 32 + 2 * c2];
        float* t0 = &tile[(k0 >> 24) * T2STRIDE + 2 * c2];
        float* t1 = &tile[(k1 >> 24) * T2STRIDE + 2 * c2];
        float* t2 = &tile[(k2 >> 24) * T2STRIDE + 2 * c2];
        float* t3 = &tile[(k3 >> 24) * T2STRIDE + 2 * c2];
        atomicAdd(t0, b2f_lo(v0)); atomicAdd(t0 + 1, b2f_hi(v0));
        atomicAdd(t1, b2f_lo(v1)); atomicAdd(t1 + 1, b2f_hi(v1));
        atomicAdd(t2, b2f_lo(v2)); atomicAdd(t2 + 1, b2f_hi(v2));
        atomicAdd(t3, b2f_lo(v3)); atomicAdd(t3 + 1, b2f_hi(v3));
    }
    for (; j < ecnt; j += 16) {
        u32 k0 = keys[j];
        u32 v0 = *(const u32*)&h2b[(size_t)(k0 & 0xFFFFFFu) * 32 + 2 * c2];
        float* t0 = &tile[(k0 >> 24) * T2STRIDE + 2 * c2];
        atomicAdd(t0, b2f_lo(v0)); atomicAdd(t0 + 1, b2f_hi(v0));
    }
    __syncthreads();

    // final: self-loop + dinv + b2 -> out (quarter-wave per node)
    float b2a = b2[2 * c2], b2b = b2[2 * c2 + 1];
    for (int node = qw; node < BNODES; node += 16) {
        int gnode = nodeBase + node;
        if (gnode >= n) break;
        u32 hv = *(const u32*)&h2b[(size_t)gnode * 32 + 2 * c2];
        float dv = dinv[gnode];
        float o0 = (tile[node * T2STRIDE + 2 * c2]     + b2f_lo(hv)) * dv + b2a;
        float o1 = (tile[node * T2STRIDE + 2 * c2 + 1] + b2f_hi(hv)) * dv + b2b;
        *(float2*)&out[(size_t)gnode * 32 + 2 * c2] = make_float2(o0, o1);
    }
}

// ---------------- launch ----------------

extern "C" void kernel_launch(void* const* d_in, const int* in_sizes, int n_in,
                              void* d_out, int out_size, void* d_ws, size_t ws_size,
                              hipStream_t stream) {
    const float* x  = (const float*)d_in[0];
    const int*   ei = (const int*)d_in[1];
    const float* W1 = (const float*)d_in[2];
    const float* b1 = (const float*)d_in[3];
    const float* W2 = (const float*)d_in[4];
    const float* b2 = (const float*)d_in[5];
    float* out = (float*)d_out;

    const int n = in_sizes[0] / 128;
    const int E = in_sizes[1] / 2;
    const int* src = ei;
    const int* dst = ei + E;
    const int NB = (n + BNODES - 1) >> BSHIFT;
    int avg = (E + NB - 1) / NB;
    int CAP = avg + avg / 8 + 256;

    char* ws = (char*)d_ws;
    size_t woff = 0;
    auto carve = [&](size_t bytes) {
        void* p = ws + woff;
        woff += (bytes + 255) & ~(size_t)255;
        return p;
    };
    int*    bcnt   = (int*)carve((size_t)NB * sizeof(int));
    u32*    binned = (u32*)carve((size_t)NB * CAP * sizeof(u32));
    float*  dinv   = (float*)carve((size_t)n * sizeof(float));
    bf16x8* Wpack  = (bf16x8*)carve(16 * 64 * sizeof(bf16x8));
    u16*    h1b    = (u16*)carve((size_t)n * 64 * sizeof(u16));
    u16*    h2b    = (u16*)carve((size_t)n * 32 * sizeof(u16));

    const int B = 256;

    // init (zero bcnt + pack W1 fragments)
    k_init<<<1, B, 0, stream>>>(W1, Wpack, bcnt, NB);

    // bucketed binning
    k_bin<<<(E + BIN_CHUNK - 1) / BIN_CHUNK, B, 0, stream>>>(src, dst, bcnt, binned, E, NB, CAP);

    // fused dinv + layer-1 MFMA transform (bf16 out)
    k_dinv_gemm1<<<NB, B, 0, stream>>>(binned, bcnt, Wpack, x, dinv, h1b, n, CAP);

    // bucket-LDS aggregate layer 1 + relu + layer-2 transform (bf16 out)
    k_agg1gemm2_c<<<NB, B, 0, stream>>>(h1b, binned, bcnt, dinv, b1, W2, h2b, n, CAP);

    // bucket-LDS final aggregation + bias -> out (fp32)
    k_agg2_b<<<NB, B, 0, stream>>>(h2b, binned, bcnt, dinv, b2, out, n, CAP);
}

// Round 10
// 225.919 us; speedup vs baseline: 4.8635x; 4.8635x over previous
//
#include <hip/hip_runtime.h>

typedef unsigned int   u32;
typedef unsigned short u16;
typedef __attribute__((ext_vector_type(8))) short bf16x8;
typedef __attribute__((ext_vector_type(4))) float f32x4;

__device__ __forceinline__ u16 f2b(float f) {
    u32 u = __float_as_uint(f);
    u += 0x7FFFu + ((u >> 16) & 1u);   // round-to-nearest-even
    return (u16)(u >> 16);
}
__device__ __forceinline__ float b2f_lo(u32 v) { return __uint_as_float(v << 16); }
__device__ __forceinline__ float b2f_hi(u32 v) { return __uint_as_float(v & 0xFFFF0000u); }
__device__ __forceinline__ u32 pack2(float a, float b) {
    return (u32)f2b(a) | ((u32)f2b(b) << 16);
}

#define BSHIFT 8                      // 256 nodes per bucket
#define BIN_CHUNK 2048                // edges per k_bin block
#define CAP_MAX 6144                  // max padded bucket capacity (24KB LDS stage)

// ---------------- init: zero bcnt + pack W1 (16 frags) + W2 (4 frags) ----------------

__global__ void k_init(const float* __restrict__ W1, const float* __restrict__ W2,
                       bf16x8* __restrict__ Wpack, bf16x8* __restrict__ W2pack,
                       int* __restrict__ bcnt, int NB) {
    int tid = threadIdx.x;
    for (int i = tid; i < NB; i += 256) bcnt[i] = 0;
    if (tid < 64) {
        int lane = tid;
#pragma unroll
        for (int ct = 0; ct < 4; ct++) {
#pragma unroll
            for (int ks = 0; ks < 4; ks++) {
                bf16x8 h;
#pragma unroll
                for (int j = 0; j < 8; j++) {
                    int k = ks * 32 + ((lane >> 4) << 3) + j;
                    int col = ct * 16 + (lane & 15);
                    h[j] = (short)f2b(W1[k * 64 + col]);
                }
                Wpack[(ct * 4 + ks) * 64 + lane] = h;
            }
        }
        // W2: 64x32 -> 2 ct x 2 ks frags
#pragma unroll
        for (int ct = 0; ct < 2; ct++) {
#pragma unroll
            for (int ks = 0; ks < 2; ks++) {
                bf16x8 h;
#pragma unroll
                for (int j = 0; j < 8; j++) {
                    int k = ks * 32 + ((lane >> 4) << 3) + j;
                    int col = ct * 16 + (lane & 15);
                    h[j] = (short)f2b(W2[k * 32 + col]);
                }
                W2pack[(ct * 2 + ks) * 64 + lane] = h;
            }
        }
    }
}

// ---------------- bucketed edge binning (R8 verbatim) ----------------

__global__ __launch_bounds__(256) void k_bin(const int* __restrict__ src,
                                             const int* __restrict__ dst,
                                             int* __restrict__ bcnt,
                                             u32* __restrict__ binned,
                                             int E, int NB, int CAP) {
    __shared__ int lh[512], ls[512], gb[512], sh[256];
    __shared__ u32 stage[BIN_CHUNK];
    __shared__ u16 sbuck[BIN_CHUNK];
    int tid = threadIdx.x;
    int base = blockIdx.x * BIN_CHUNK;
    int cnt = E - base;
    if (cnt > BIN_CHUNK) cnt = BIN_CHUNK;

    for (int i = tid; i < 512; i += 256) lh[i] = 0;
    __syncthreads();

    const int T = BIN_CHUNK / 256;
    int bk[T], r[T];
    u32 key[T];
#pragma unroll
    for (int t = 0; t < T; t++) {
        int i = base + t * 256 + tid;
        bk[t] = -1;
        if (i < E) {
            int dv = dst[i];
            bk[t] = dv >> BSHIFT;
            key[t] = ((u32)(dv & 255) << 24) | (u32)src[i];
            r[t] = atomicAdd(&lh[bk[t]], 1);
        }
    }
    __syncthreads();
    {
        int a0 = lh[2 * tid], a1 = lh[2 * tid + 1];
        int sum2 = a0 + a1;
        sh[tid] = sum2;
        __syncthreads();
        for (int dd = 1; dd < 256; dd <<= 1) {
            int x = tid >= dd ? sh[tid - dd] : 0;
            __syncthreads();
            sh[tid] += x;
            __syncthreads();
        }
        int excl = sh[tid] - sum2;
        ls[2 * tid] = excl;
        ls[2 * tid + 1] = excl + a0;
    }
    for (int b = tid; b < NB; b += 256) {
        int c = lh[b];
        gb[b] = c ? atomicAdd(&bcnt[b], c) : 0;
    }
    __syncthreads();
#pragma unroll
    for (int t = 0; t < T; t++) {
        if (bk[t] >= 0) {
            int slot = ls[bk[t]] + r[t];
            stage[slot] = key[t];
            sbuck[slot] = (u16)bk[t];
        }
    }
    __syncthreads();
    for (int j = tid; j < cnt; j += 256) {
        u32 e = stage[j];
        int b = sbuck[j];
        int p = gb[b] + (j - ls[b]);
        if (p < CAP) binned[(size_t)b * CAP + p] = e;
    }
}

// ---------------- fused CSR + gemm1 (R8; h1b now CHUNK-MAJOR [4][n][16]) ----------------

__global__ __launch_bounds__(256) void k_csr_gemm1(const u32* __restrict__ binned,
                                                   const int* __restrict__ bcnt,
                                                   const bf16x8* __restrict__ Wpack,
                                                   const float* __restrict__ x,
                                                   float* __restrict__ dinv,
                                                   int2* __restrict__ offse,
                                                   int* __restrict__ esrc,
                                                   u16* __restrict__ h1b,
                                                   int n, int CAP) {
    __shared__ u32 stagec[CAP_MAX];
    __shared__ int lcnt[256], lcur[256], sh[256];
    __shared__ float dinv_sh[256];
    int tid = threadIdx.x;
    int b = blockIdx.x;
    size_t base = (size_t)b * CAP;
    int nodeBase = b << BSHIFT;
    int ecnt = bcnt[b];
    if (ecnt > CAP) ecnt = CAP;
    lcnt[tid] = 0;
    __syncthreads();
    for (int j = tid; j < ecnt; j += 256) {
        u32 e = binned[base + j];
        stagec[j] = e;
        atomicAdd(&lcnt[e >> 24], 1);
    }
    __syncthreads();
    int v = lcnt[tid];
    sh[tid] = v;
    __syncthreads();
    for (int d = 1; d < 256; d <<= 1) {
        int xx = tid >= d ? sh[tid - d] : 0;
        __syncthreads();
        sh[tid] += xx;
        __syncthreads();
    }
    int excl = sh[tid] - v;
    int node = nodeBase + tid;
    float dvt = rsqrtf((float)(v + 1));
    dinv_sh[tid] = dvt;
    if (node < n) {
        offse[node] = make_int2((int)base + excl, (int)base + excl + v);
        dinv[node] = dvt;
    }
    lcur[tid] = excl;
    __syncthreads();
    for (int j = tid; j < ecnt; j += 256) {
        u32 e = stagec[j];
        int p = atomicAdd(&lcur[e >> 24], 1);
        esrc[base + p] = (int)(e & 0xFFFFFFu);
    }

    // ---- phase 2: gemm1 for this bucket's rows ----
    int wv = tid >> 6, lane = tid & 63;
    bf16x8 bfr[16];
#pragma unroll
    for (int f = 0; f < 16; f++) bfr[f] = Wpack[f * 64 + lane];
    size_t cs = (size_t)n * 16;   // chunk stride (u16 units)

    for (int t = wv; t < 16; t += 4) {
        int rowBase = nodeBase + t * 16;
        if (rowBase >= n) break;
        f32x4 acc[4];
#pragma unroll
        for (int ct = 0; ct < 4; ct++) acc[ct] = (f32x4){0.f, 0.f, 0.f, 0.f};

        int r0 = rowBase + (lane & 15);
        if (r0 >= n) r0 = n - 1;           // clamp: D row i only uses A row i
        const float* xr = x + (size_t)r0 * 128 + ((lane >> 4) << 3);
#pragma unroll
        for (int ks = 0; ks < 4; ks++) {
            float4 p0 = *(const float4*)(xr + ks * 32);
            float4 p1 = *(const float4*)(xr + ks * 32 + 4);
            bf16x8 a;
            a[0] = (short)f2b(p0.x); a[1] = (short)f2b(p0.y);
            a[2] = (short)f2b(p0.z); a[3] = (short)f2b(p0.w);
            a[4] = (short)f2b(p1.x); a[5] = (short)f2b(p1.y);
            a[6] = (short)f2b(p1.z); a[7] = (short)f2b(p1.w);
#pragma unroll
            for (int ct = 0; ct < 4; ct++)
                acc[ct] = __builtin_amdgcn_mfma_f32_16x16x32_bf16(a, bfr[ct * 4 + ks], acc[ct], 0, 0, 0);
        }
        // C/D layout: col = lane&15, row = (lane>>4)*4 + r  [m89-verified]
        int lrb = t * 16 + ((lane >> 4) << 2);
#pragma unroll
        for (int r = 0; r < 4; r++) {
            int lrow = lrb + r;
            int row = nodeBase + lrow;
            float dv = dinv_sh[lrow];
#pragma unroll
            for (int ct = 0; ct < 4; ct++) {
                float o = acc[ct][r] * dv;
                float onb = __shfl_xor(o, 1);   // neighbor col
                if (!(lane & 1) && row < n) {
                    // chunk-major: h1b[ct][row][col]
                    *(u32*)&h1b[(size_t)ct * cs + (size_t)row * 16 + (lane & 15)] = pack2(o, onb);
                }
            }
        }
    }
}

// ---------------- L2-resident chunked gather (layer 1), one pass per 16-ch chunk ----------------
// half-wave per node; 4 edge-slots of 8 lanes; gathers 32B rows from the 3.2MB chunk.

__global__ __launch_bounds__(256) void k_gather1(const u16* __restrict__ h1c,  // chunk base
                                                 const int2* __restrict__ offse,
                                                 const int* __restrict__ esrc,
                                                 float* __restrict__ aggc,     // [n][16] f32
                                                 int n) {
    int node = (int)((blockIdx.x * blockDim.x + threadIdx.x) >> 5);
    if (node >= n) return;
    int l = threadIdx.x & 31;
    int slot = l >> 3;            // 0..3
    int j = l & 7;                // channel pair 2j, 2j+1
    int2 ov = offse[node];
    float a0 = 0.f, a1 = 0.f;
    for (int e = ov.x + slot; e < ov.y; e += 4) {
        int s = esrc[e];
        u32 v = *(const u32*)&h1c[(size_t)s * 16 + 2 * j];
        a0 += b2f_lo(v); a1 += b2f_hi(v);
    }
    a0 += __shfl_xor(a0, 8);  a1 += __shfl_xor(a1, 8);
    a0 += __shfl_xor(a0, 16); a1 += __shfl_xor(a1, 16);
    if (slot == 0) {
        u32 v = *(const u32*)&h1c[(size_t)node * 16 + 2 * j];   // self-loop
        a0 += b2f_lo(v); a1 += b2f_hi(v);
        *(float2*)&aggc[(size_t)node * 16 + 2 * j] = make_float2(a0, a1);
    }
}

// ---------------- gemm2 via MFMA: h2b = bf16((relu(agg*dv+b1) @ W2) * dv) ----------------
// agg chunk-major [4][n][16] f32; wave per 16 nodes.

__global__ __launch_bounds__(256) void k_gemm2_mfma(const float* __restrict__ agg,
                                                    const float* __restrict__ dinv,
                                                    const float* __restrict__ b1,
                                                    const bf16x8* __restrict__ W2pack,
                                                    u16* __restrict__ h2b,
                                                    int n, int ntiles) {
    int gwave = (int)((blockIdx.x * blockDim.x + threadIdx.x) >> 6);
    int lane = threadIdx.x & 63;
    if (gwave >= ntiles) return;
    int rowBase = gwave * 16;

    bf16x8 bfr[4];
#pragma unroll
    for (int f = 0; f < 4; f++) bfr[f] = W2pack[f * 64 + lane];
    float b1r[16];
#pragma unroll
    for (int ks = 0; ks < 2; ks++)
#pragma unroll
        for (int j = 0; j < 8; j++)
            b1r[ks * 8 + j] = b1[ks * 32 + ((lane >> 4) << 3) + j];

    int r0 = rowBase + (lane & 15);
    if (r0 >= n) r0 = n - 1;
    float dv0 = dinv[r0];
    size_t cs = (size_t)n * 16;

    f32x4 acc[2];
    acc[0] = (f32x4){0.f, 0.f, 0.f, 0.f};
    acc[1] = (f32x4){0.f, 0.f, 0.f, 0.f};
#pragma unroll
    for (int ks = 0; ks < 2; ks++) {
        int c0 = 2 * ks + ((lane >> 4) >> 1);          // chunk index
        int j0 = ((lane >> 4) & 1) << 3;               // 0 or 8 within chunk
        const float* ap = agg + (size_t)c0 * cs + (size_t)r0 * 16 + j0;
        float4 p0 = *(const float4*)ap;
        float4 p1 = *(const float4*)(ap + 4);
        float t[8] = {p0.x, p0.y, p0.z, p0.w, p1.x, p1.y, p1.z, p1.w};
        bf16x8 a;
#pragma unroll
        for (int j = 0; j < 8; j++) {
            float av = t[j] * dv0 + b1r[ks * 8 + j];
            a[j] = (short)f2b(av > 0.f ? av : 0.f);
        }
#pragma unroll
        for (int ct = 0; ct < 2; ct++)
            acc[ct] = __builtin_amdgcn_mfma_f32_16x16x32_bf16(a, bfr[ct * 2 + ks], acc[ct], 0, 0, 0);
    }

    int rbase = rowBase + ((lane >> 4) << 2);
#pragma unroll
    for (int r = 0; r < 4; r++) {
        int row = rbase + r;
        float dv = (row < n) ? dinv[row] : 0.f;
#pragma unroll
        for (int ct = 0; ct < 2; ct++) {
            float o = acc[ct][r] * dv;
            float onb = __shfl_xor(o, 1);
            if (!(lane & 1) && row < n) {
                *(u32*)&h2b[(size_t)row * 32 + ct * 16 + (lane & 15)] = pack2(o, onb);
            }
        }
    }
}

// ---------------- final aggregation -> out (R8 verbatim) ----------------

__global__ __launch_bounds__(256) void k_agg2(const u16* __restrict__ h2b,
                                              const int2* __restrict__ offse,
                                              const int* __restrict__ esrc,
                                              const float* __restrict__ dinv,
                                              const float* __restrict__ b2,
                                              float* __restrict__ out, int n) {
    int wid = (int)((blockIdx.x * blockDim.x + threadIdx.x) >> 6);
    int lane = threadIdx.x & 63;
    int g = lane >> 4, c2 = lane & 15;
    if (wid >= n) return;
    int2 ov = offse[wid];
    int e1 = ov.y;
    float a0 = 0.f, a1 = 0.f, a2 = 0.f, a3 = 0.f;
    int e = ov.x + g;
    for (; e + 4 < e1; e += 8) {
        int s0 = esrc[e], s1 = esrc[e + 4];
        u32 v0 = *(const u32*)&h2b[(size_t)s0 * 32 + 2 * c2];
        u32 v1 = *(const u32*)&h2b[(size_t)s1 * 32 + 2 * c2];
        a0 += b2f_lo(v0); a1 += b2f_hi(v0);
        a2 += b2f_lo(v1); a3 += b2f_hi(v1);
    }
    if (e < e1) {
        int s = esrc[e];
        u32 v = *(const u32*)&h2b[(size_t)s * 32 + 2 * c2];
        a0 += b2f_lo(v); a1 += b2f_hi(v);
    }
    a0 += a2; a1 += a3;
    a0 += __shfl_xor(a0, 16); a0 += __shfl_xor(a0, 32);
    a1 += __shfl_xor(a1, 16); a1 += __shfl_xor(a1, 32);
    if (g == 0) {
        u32 v = *(const u32*)&h2b[(size_t)wid * 32 + 2 * c2];   // self-loop
        a0 += b2f_lo(v); a1 += b2f_hi(v);
        float dv = dinv[wid];
        float2 o = make_float2(a0 * dv + b2[2 * c2], a1 * dv + b2[2 * c2 + 1]);
        *(float2*)&out[(size_t)wid * 32 + 2 * c2] = o;
    }
}

// ---------------- launch ----------------

extern "C" void kernel_launch(void* const* d_in, const int* in_sizes, int n_in,
                              void* d_out, int out_size, void* d_ws, size_t ws_size,
                              hipStream_t stream) {
    const float* x  = (const float*)d_in[0];
    const int*   ei = (const int*)d_in[1];
    const float* W1 = (const float*)d_in[2];
    const float* b1 = (const float*)d_in[3];
    const float* W2 = (const float*)d_in[4];
    const float* b2 = (const float*)d_in[5];
    float* out = (float*)d_out;

    const int n = in_sizes[0] / 128;
    const int E = in_sizes[1] / 2;
    const int* src = ei;
    const int* dst = ei + E;
    const int NB = (n + 255) >> BSHIFT;
    int avg = (E + NB - 1) / NB;
    int CAP = avg + avg / 8 + 512;
    if (CAP > CAP_MAX) CAP = CAP_MAX;

    char* ws = (char*)d_ws;
    size_t woff = 0;
    auto carve = [&](size_t bytes) {
        void* p = ws + woff;
        woff += (bytes + 255) & ~(size_t)255;
        return p;
    };
    int*    bcnt   = (int*)carve((size_t)NB * sizeof(int));
    u32*    binned = (u32*)carve((size_t)NB * CAP * sizeof(u32));
    int2*   offse  = (int2*)carve((size_t)n * sizeof(int2));
    float*  dinv   = (float*)carve((size_t)n * sizeof(float));
    int*    esrc   = (int*)carve((size_t)NB * CAP * sizeof(int));
    bf16x8* Wpack  = (bf16x8*)carve(16 * 64 * sizeof(bf16x8));
    bf16x8* W2pack = (bf16x8*)carve(4 * 64 * sizeof(bf16x8));
    u16*    h1b    = (u16*)carve((size_t)n * 64 * sizeof(u16));   // chunk-major [4][n][16]
    float*  agg    = (float*)carve((size_t)n * 64 * sizeof(float)); // chunk-major [4][n][16]
    u16*    h2b    = (u16*)carve((size_t)n * 32 * sizeof(u16));

    const int B = 256;

    // init (zero bcnt + pack W1/W2 fragments)
    k_init<<<1, B, 0, stream>>>(W1, W2, Wpack, W2pack, bcnt, NB);

    // bucketed binning
    k_bin<<<(E + BIN_CHUNK - 1) / BIN_CHUNK, B, 0, stream>>>(src, dst, bcnt, binned, E, NB, CAP);

    // fused CSR build + layer-1 MFMA transform (chunk-major bf16 out)
    k_csr_gemm1<<<NB, B, 0, stream>>>(binned, bcnt, Wpack, x, dinv, offse, esrc, h1b, n, CAP);

    // layer-1 aggregation: 4 L2-resident chunk passes
    size_t cs = (size_t)n * 16;
    int gGather = (n + 7) / 8;
    for (int p = 0; p < 4; p++) {
        k_gather1<<<gGather, B, 0, stream>>>(h1b + p * cs, offse, esrc, agg + p * cs, n);
    }

    // relu + layer-2 transform via MFMA (bf16 out)
    int ntiles2 = (n + 15) / 16;
    k_gemm2_mfma<<<(ntiles2 + 3) / 4, B, 0, stream>>>(agg, dinv, b1, W2pack, h2b, n, ntiles2);

    // final aggregation + bias -> out (fp32)
    k_agg2<<<(n + 3) / 4, B, 0, stream>>>(h2b, offse, esrc, dinv, b2, out, n);
}

// Round 11
// 165.137 us; speedup vs baseline: 6.6535x; 1.3681x over previous
//
#include <hip/hip_runtime.h>

typedef unsigned int   u32;
typedef unsigned short u16;
typedef __attribute__((ext_vector_type(8))) short bf16x8;
typedef __attribute__((ext_vector_type(4))) float f32x4;

__device__ __forceinline__ u16 f2b(float f) {
    u32 u = __float_as_uint(f);
    u += 0x7FFFu + ((u >> 16) & 1u);   // round-to-nearest-even
    return (u16)(u >> 16);
}
__device__ __forceinline__ float b2f_lo(u32 v) { return __uint_as_float(v << 16); }
__device__ __forceinline__ float b2f_hi(u32 v) { return __uint_as_float(v & 0xFFFF0000u); }
__device__ __forceinline__ u32 pack2(float a, float b) {
    return (u32)f2b(a) | ((u32)f2b(b) << 16);
}

#define BSHIFT 8                      // 256 nodes per bucket
#define BIN_CHUNK 2048                // edges per k_bin block
#define CAP_MAX 6144                  // max padded bucket capacity (24KB LDS stage)

// ---------------- init: zero bucket counters + pack W1 MFMA B-fragments ----------------

__global__ void k_init(const float* __restrict__ W1, bf16x8* __restrict__ Wpack,
                       int* __restrict__ bcnt, int NB) {
    int tid = threadIdx.x;
    for (int i = tid; i < NB; i += 256) bcnt[i] = 0;
    if (tid < 64) {
        int lane = tid;
#pragma unroll
        for (int ct = 0; ct < 4; ct++) {
#pragma unroll
            for (int ks = 0; ks < 4; ks++) {
                bf16x8 h;
#pragma unroll
                for (int j = 0; j < 8; j++) {
                    int k = ks * 32 + ((lane >> 4) << 3) + j;
                    int col = ct * 16 + (lane & 15);
                    h[j] = (short)f2b(W1[k * 64 + col]);
                }
                Wpack[(ct * 4 + ks) * 64 + lane] = h;
            }
        }
    }
}

// ---------------- bucketed edge binning (R8 verbatim) ----------------

__global__ __launch_bounds__(256) void k_bin(const int* __restrict__ src,
                                             const int* __restrict__ dst,
                                             int* __restrict__ bcnt,
                                             u32* __restrict__ binned,
                                             int E, int NB, int CAP) {
    __shared__ int lh[512], ls[512], gb[512], sh[256];
    __shared__ u32 stage[BIN_CHUNK];
    __shared__ u16 sbuck[BIN_CHUNK];
    int tid = threadIdx.x;
    int base = blockIdx.x * BIN_CHUNK;
    int cnt = E - base;
    if (cnt > BIN_CHUNK) cnt = BIN_CHUNK;

    for (int i = tid; i < 512; i += 256) lh[i] = 0;
    __syncthreads();

    const int T = BIN_CHUNK / 256;
    int bk[T], r[T];
    u32 key[T];
#pragma unroll
    for (int t = 0; t < T; t++) {
        int i = base + t * 256 + tid;
        bk[t] = -1;
        if (i < E) {
            int dv = dst[i];
            bk[t] = dv >> BSHIFT;
            key[t] = ((u32)(dv & 255) << 24) | (u32)src[i];
            r[t] = atomicAdd(&lh[bk[t]], 1);
        }
    }
    __syncthreads();
    {
        int a0 = lh[2 * tid], a1 = lh[2 * tid + 1];
        int sum2 = a0 + a1;
        sh[tid] = sum2;
        __syncthreads();
        for (int dd = 1; dd < 256; dd <<= 1) {
            int x = tid >= dd ? sh[tid - dd] : 0;
            __syncthreads();
            sh[tid] += x;
            __syncthreads();
        }
        int excl = sh[tid] - sum2;
        ls[2 * tid] = excl;
        ls[2 * tid + 1] = excl + a0;
    }
    for (int b = tid; b < NB; b += 256) {
        int c = lh[b];
        gb[b] = c ? atomicAdd(&bcnt[b], c) : 0;
    }
    __syncthreads();
#pragma unroll
    for (int t = 0; t < T; t++) {
        if (bk[t] >= 0) {
            int slot = ls[bk[t]] + r[t];
            stage[slot] = key[t];
            sbuck[slot] = (u16)bk[t];
        }
    }
    __syncthreads();
    for (int j = tid; j < cnt; j += 256) {
        u32 e = stage[j];
        int b = sbuck[j];
        int p = gb[b] + (j - ls[b]);
        if (p < CAP) binned[(size_t)b * CAP + p] = e;
    }
}

// ---------------- fused CSR + gemm1 (R8 verbatim, h1b row-major [n][64]) ----------------

__global__ __launch_bounds__(256) void k_csr_gemm1(const u32* __restrict__ binned,
                                                   const int* __restrict__ bcnt,
                                                   const bf16x8* __restrict__ Wpack,
                                                   const float* __restrict__ x,
                                                   float* __restrict__ dinv,
                                                   int2* __restrict__ offse,
                                                   int* __restrict__ esrc,
                                                   u16* __restrict__ h1b,
                                                   int n, int CAP) {
    __shared__ u32 stagec[CAP_MAX];
    __shared__ int lcnt[256], lcur[256], sh[256];
    __shared__ float dinv_sh[256];
    int tid = threadIdx.x;
    int b = blockIdx.x;
    size_t base = (size_t)b * CAP;
    int nodeBase = b << BSHIFT;
    int ecnt = bcnt[b];
    if (ecnt > CAP) ecnt = CAP;
    lcnt[tid] = 0;
    __syncthreads();
    for (int j = tid; j < ecnt; j += 256) {
        u32 e = binned[base + j];
        stagec[j] = e;
        atomicAdd(&lcnt[e >> 24], 1);
    }
    __syncthreads();
    int v = lcnt[tid];
    sh[tid] = v;
    __syncthreads();
    for (int d = 1; d < 256; d <<= 1) {
        int xx = tid >= d ? sh[tid - d] : 0;
        __syncthreads();
        sh[tid] += xx;
        __syncthreads();
    }
    int excl = sh[tid] - v;
    int node = nodeBase + tid;
    float dvt = rsqrtf((float)(v + 1));
    dinv_sh[tid] = dvt;
    if (node < n) {
        offse[node] = make_int2((int)base + excl, (int)base + excl + v);
        dinv[node] = dvt;
    }
    lcur[tid] = excl;
    __syncthreads();
    for (int j = tid; j < ecnt; j += 256) {
        u32 e = stagec[j];
        int p = atomicAdd(&lcur[e >> 24], 1);
        esrc[base + p] = (int)(e & 0xFFFFFFu);
    }

    // ---- phase 2: gemm1 for this bucket's rows ----
    int wv = tid >> 6, lane = tid & 63;
    bf16x8 bfr[16];
#pragma unroll
    for (int f = 0; f < 16; f++) bfr[f] = Wpack[f * 64 + lane];

    for (int t = wv; t < 16; t += 4) {
        int rowBase = nodeBase + t * 16;
        if (rowBase >= n) break;
        f32x4 acc[4];
#pragma unroll
        for (int ct = 0; ct < 4; ct++) acc[ct] = (f32x4){0.f, 0.f, 0.f, 0.f};

        int r0 = rowBase + (lane & 15);
        if (r0 >= n) r0 = n - 1;           // clamp: D row i only uses A row i
        const float* xr = x + (size_t)r0 * 128 + ((lane >> 4) << 3);
#pragma unroll
        for (int ks = 0; ks < 4; ks++) {
            float4 p0 = *(const float4*)(xr + ks * 32);
            float4 p1 = *(const float4*)(xr + ks * 32 + 4);
            bf16x8 a;
            a[0] = (short)f2b(p0.x); a[1] = (short)f2b(p0.y);
            a[2] = (short)f2b(p0.z); a[3] = (short)f2b(p0.w);
            a[4] = (short)f2b(p1.x); a[5] = (short)f2b(p1.y);
            a[6] = (short)f2b(p1.z); a[7] = (short)f2b(p1.w);
#pragma unroll
            for (int ct = 0; ct < 4; ct++)
                acc[ct] = __builtin_amdgcn_mfma_f32_16x16x32_bf16(a, bfr[ct * 4 + ks], acc[ct], 0, 0, 0);
        }
        // C/D layout: col = lane&15, row = (lane>>4)*4 + r  [m89-verified]
        int lrb = t * 16 + ((lane >> 4) << 2);
#pragma unroll
        for (int r = 0; r < 4; r++) {
            int lrow = lrb + r;
            int row = nodeBase + lrow;
            float dv = dinv_sh[lrow];
#pragma unroll
            for (int ct = 0; ct < 4; ct++) {
                float o = acc[ct][r] * dv;
                float onb = __shfl_xor(o, 1);   // neighbor col
                if (!(lane & 1) && row < n) {
                    *(u32*)&h1b[(size_t)row * 64 + ct * 16 + (lane & 15)] = pack2(o, onb);
                }
            }
        }
    }
}

// ---------------- fused agg1 + relu + gemm2: 8 groups x 8 lanes, uint4 gathers ----------------
// group g owns edges e0+g, e0+g+8, ...; lane jj covers channels 8*jj..8*jj+7 (16B).
// 2 slots/group -> 16 outstanding 128B-row gathers per wave; ~1.5 dependent rounds at deg=16.

__global__ __launch_bounds__(256) void k_agg1gemm2(const u16* __restrict__ h1b,
                                                   const int2* __restrict__ offse,
                                                   const int* __restrict__ esrc,
                                                   const float* __restrict__ dinv,
                                                   const float* __restrict__ b1,
                                                   const float* __restrict__ W2,
                                                   u16* __restrict__ h2b, int n) {
    __shared__ float aggL[4][64];
    int warp = threadIdx.x >> 6, lane = threadIdx.x & 63;
    int g = lane >> 3;            // 8 groups
    int jj = lane & 7;            // channels 8*jj..+7
    int half = lane >> 5, c2o = lane & 31;
    float w2r[32];
#pragma unroll
    for (int kk = 0; kk < 32; kk++) w2r[kk] = W2[(half * 32 + kk) * 32 + c2o];
    float b1r[8];
#pragma unroll
    for (int t = 0; t < 8; t++) b1r[t] = b1[8 * jj + t];
    int nwaves = (gridDim.x * blockDim.x) >> 6;
    for (int wid = (int)((blockIdx.x * blockDim.x + threadIdx.x) >> 6); wid < n;
         wid += nwaves) {
        int2 ov = offse[wid];
        int e1 = ov.y;
        float a[8] = {0.f, 0.f, 0.f, 0.f, 0.f, 0.f, 0.f, 0.f};
        float bsl[8] = {0.f, 0.f, 0.f, 0.f, 0.f, 0.f, 0.f, 0.f};
        if (g == 0) {   // self-loop row (overlaps with first edge gathers)
            uint4 v = *(const uint4*)&h1b[(size_t)wid * 64 + 8 * jj];
            a[0] += b2f_lo(v.x); a[1] += b2f_hi(v.x); a[2] += b2f_lo(v.y); a[3] += b2f_hi(v.y);
            a[4] += b2f_lo(v.z); a[5] += b2f_hi(v.z); a[6] += b2f_lo(v.w); a[7] += b2f_hi(v.w);
        }
        int e = ov.x + g;
        for (; e + 8 < e1; e += 16) {         // 2 slots
            int s0 = esrc[e], s1 = esrc[e + 8];
            uint4 v0 = *(const uint4*)&h1b[(size_t)s0 * 64 + 8 * jj];
            uint4 v1 = *(const uint4*)&h1b[(size_t)s1 * 64 + 8 * jj];
            a[0] += b2f_lo(v0.x); a[1] += b2f_hi(v0.x); a[2] += b2f_lo(v0.y); a[3] += b2f_hi(v0.y);
            a[4] += b2f_lo(v0.z); a[5] += b2f_hi(v0.z); a[6] += b2f_lo(v0.w); a[7] += b2f_hi(v0.w);
            bsl[0] += b2f_lo(v1.x); bsl[1] += b2f_hi(v1.x); bsl[2] += b2f_lo(v1.y); bsl[3] += b2f_hi(v1.y);
            bsl[4] += b2f_lo(v1.z); bsl[5] += b2f_hi(v1.z); bsl[6] += b2f_lo(v1.w); bsl[7] += b2f_hi(v1.w);
        }
        for (; e < e1; e += 8) {
            int s = esrc[e];
            uint4 v = *(const uint4*)&h1b[(size_t)s * 64 + 8 * jj];
            a[0] += b2f_lo(v.x); a[1] += b2f_hi(v.x); a[2] += b2f_lo(v.y); a[3] += b2f_hi(v.y);
            a[4] += b2f_lo(v.z); a[5] += b2f_hi(v.z); a[6] += b2f_lo(v.w); a[7] += b2f_hi(v.w);
        }
#pragma unroll
        for (int t = 0; t < 8; t++) a[t] += bsl[t];
#pragma unroll
        for (int t = 0; t < 8; t++) { a[t] += __shfl_xor(a[t], 8); }
#pragma unroll
        for (int t = 0; t < 8; t++) { a[t] += __shfl_xor(a[t], 16); }
#pragma unroll
        for (int t = 0; t < 8; t++) { a[t] += __shfl_xor(a[t], 32); }
        float dv = dinv[wid];
        if (g == 0) {
            float av[8];
#pragma unroll
            for (int t = 0; t < 8; t++) {
                float u = a[t] * dv + b1r[t];
                av[t] = u > 0.f ? u : 0.f;
            }
            *(float4*)&aggL[warp][8 * jj]     = make_float4(av[0], av[1], av[2], av[3]);
            *(float4*)&aggL[warp][8 * jj + 4] = make_float4(av[4], av[5], av[6], av[7]);
        }
        asm volatile("s_waitcnt lgkmcnt(0)" ::: "memory");  // wave-internal sync
        float acc = 0.f;
#pragma unroll
        for (int kk = 0; kk < 32; kk += 4) {
            float4 avv = *(const float4*)&aggL[warp][half * 32 + kk];
            acc += avv.x * w2r[kk] + avv.y * w2r[kk + 1] + avv.z * w2r[kk + 2] + avv.w * w2r[kk + 3];
        }
        acc += __shfl_xor(acc, 32);
        if (half == 0) h2b[(size_t)wid * 32 + c2o] = f2b(acc * dv);
    }
}

// ---------------- final aggregation -> out: 8 groups x 8 lanes, uint2 gathers ----------------
// lane jj covers channels 4*jj..4*jj+3 (8B); 2 slots/group.

__global__ __launch_bounds__(256) void k_agg2(const u16* __restrict__ h2b,
                                              const int2* __restrict__ offse,
                                              const int* __restrict__ esrc,
                                              const float* __restrict__ dinv,
                                              const float* __restrict__ b2,
                                              float* __restrict__ out, int n) {
    int wid = (int)((blockIdx.x * blockDim.x + threadIdx.x) >> 6);
    int lane = threadIdx.x & 63;
    int g = lane >> 3;            // 8 groups
    int jj = lane & 7;            // channels 4*jj..+3
    if (wid >= n) return;
    int2 ov = offse[wid];
    int e1 = ov.y;
    float a0 = 0.f, a1 = 0.f, a2 = 0.f, a3 = 0.f;
    float c0 = 0.f, c1 = 0.f, c2 = 0.f, c3 = 0.f;
    if (g == 0) {   // self-loop
        uint2 v = *(const uint2*)&h2b[(size_t)wid * 32 + 4 * jj];
        a0 += b2f_lo(v.x); a1 += b2f_hi(v.x); a2 += b2f_lo(v.y); a3 += b2f_hi(v.y);
    }
    int e = ov.x + g;
    for (; e + 8 < e1; e += 16) {           // 2 slots
        int s0 = esrc[e], s1 = esrc[e + 8];
        uint2 v0 = *(const uint2*)&h2b[(size_t)s0 * 32 + 4 * jj];
        uint2 v1 = *(const uint2*)&h2b[(size_t)s1 * 32 + 4 * jj];
        a0 += b2f_lo(v0.x); a1 += b2f_hi(v0.x); a2 += b2f_lo(v0.y); a3 += b2f_hi(v0.y);
        c0 += b2f_lo(v1.x); c1 += b2f_hi(v1.x); c2 += b2f_lo(v1.y); c3 += b2f_hi(v1.y);
    }
    for (; e < e1; e += 8) {
        int s = esrc[e];
        uint2 v = *(const uint2*)&h2b[(size_t)s * 32 + 4 * jj];
        a0 += b2f_lo(v.x); a1 += b2f_hi(v.x); a2 += b2f_lo(v.y); a3 += b2f_hi(v.y);
    }
    a0 += c0; a1 += c1; a2 += c2; a3 += c3;
    a0 += __shfl_xor(a0, 8);  a1 += __shfl_xor(a1, 8);  a2 += __shfl_xor(a2, 8);  a3 += __shfl_xor(a3, 8);
    a0 += __shfl_xor(a0, 16); a1 += __shfl_xor(a1, 16); a2 += __shfl_xor(a2, 16); a3 += __shfl_xor(a3, 16);
    a0 += __shfl_xor(a0, 32); a1 += __shfl_xor(a1, 32); a2 += __shfl_xor(a2, 32); a3 += __shfl_xor(a3, 32);
    if (g == 0) {
        float dv = dinv[wid];
        float4 o = make_float4(a0 * dv + b2[4 * jj],     a1 * dv + b2[4 * jj + 1],
                               a2 * dv + b2[4 * jj + 2], a3 * dv + b2[4 * jj + 3]);
        *(float4*)&out[(size_t)wid * 32 + 4 * jj] = o;
    }
}

// ---------------- launch ----------------

extern "C" void kernel_launch(void* const* d_in, const int* in_sizes, int n_in,
                              void* d_out, int out_size, void* d_ws, size_t ws_size,
                              hipStream_t stream) {
    const float* x  = (const float*)d_in[0];
    const int*   ei = (const int*)d_in[1];
    const float* W1 = (const float*)d_in[2];
    const float* b1 = (const float*)d_in[3];
    const float* W2 = (const float*)d_in[4];
    const float* b2 = (const float*)d_in[5];
    float* out = (float*)d_out;

    const int n = in_sizes[0] / 128;
    const int E = in_sizes[1] / 2;
    const int* src = ei;
    const int* dst = ei + E;
    const int NB = (n + 255) >> BSHIFT;
    int avg = (E + NB - 1) / NB;
    int CAP = avg + avg / 8 + 512;
    if (CAP > CAP_MAX) CAP = CAP_MAX;

    char* ws = (char*)d_ws;
    size_t woff = 0;
    auto carve = [&](size_t bytes) {
        void* p = ws + woff;
        woff += (bytes + 255) & ~(size_t)255;
        return p;
    };
    int*    bcnt   = (int*)carve((size_t)NB * sizeof(int));
    u32*    binned = (u32*)carve((size_t)NB * CAP * sizeof(u32));
    int2*   offse  = (int2*)carve((size_t)n * sizeof(int2));
    float*  dinv   = (float*)carve((size_t)n * sizeof(float));
    int*    esrc   = (int*)carve((size_t)NB * CAP * sizeof(int));
    bf16x8* Wpack  = (bf16x8*)carve(16 * 64 * sizeof(bf16x8));
    u16*    h1b    = (u16*)carve((size_t)n * 64 * sizeof(u16));
    u16*    h2b    = (u16*)carve((size_t)n * 32 * sizeof(u16));

    const int B = 256;

    // init (zero bcnt + pack W1 fragments)
    k_init<<<1, B, 0, stream>>>(W1, Wpack, bcnt, NB);

    // bucketed binning
    k_bin<<<(E + BIN_CHUNK - 1) / BIN_CHUNK, B, 0, stream>>>(src, dst, bcnt, binned, E, NB, CAP);

    // fused CSR build + layer-1 MFMA transform (bf16 out)
    k_csr_gemm1<<<NB, B, 0, stream>>>(binned, bcnt, Wpack, x, dinv, offse, esrc, h1b, n, CAP);

    // fused: aggregate layer 1 + relu + layer-2 transform (bf16 out)
    k_agg1gemm2<<<2048, B, 0, stream>>>(h1b, offse, esrc, dinv, b1, W2, h2b, n);

    // final aggregation + bias -> out (fp32)
    k_agg2<<<(n + 3) / 4, B, 0, stream>>>(h2b, offse, esrc, dinv, b2, out, n);
}